// Round 1
// 3652.613 us; speedup vs baseline: 2.8725x; 2.8725x over previous
//
#include <hip/hip_runtime.h>

typedef unsigned short ushort_t;
typedef unsigned long long u64;
typedef __attribute__((ext_vector_type(8))) __bf16 bf16x8;
typedef __attribute__((ext_vector_type(4))) float f32x4;

#define B 256
#define TENC 512
#define TDEC 64
#define DIN 64
#define HD 512
#define OD 512
#define GG 128          // 8 batch-groups x 16 unit-groups
#define NGRP 16         // WGs per batch-group (unit-groups)
#define KTOT 576        // 512 (h) + 64 (x)
#define KI 18           // K iters of 32
#define NT 512          // threads per block

__device__ __forceinline__ float b2f(ushort_t v) {
  union { unsigned u; float f; } x; x.u = ((unsigned)v) << 16; return x.f;
}
__device__ __forceinline__ ushort_t f2b(float f) {
  union { float f; unsigned u; } x; x.f = f;
  unsigned r = x.u + 0x7fffu + ((x.u >> 16) & 1u);   // RNE
  return (ushort_t)(r >> 16);
}
__device__ __forceinline__ float sigmf(float x) { return 1.f / (1.f + __expf(-x)); }
__device__ __forceinline__ float tanhf_fast(float x) {
  float e = __expf(2.f * x);
  return 1.f - 2.f / (e + 1.f);
}
__device__ __forceinline__ float ld_elem(const void* p, size_t i, bool f32) {
  return f32 ? ((const float*)p)[i] : b2f(((const ushort_t*)p)[i]);
}
__device__ __forceinline__ bf16x8 cvt8(const float* f) {
  f32x4 u = *(const f32x4*)f, v = *(const f32x4*)(f + 4);
  bf16x8 r;
  r[0] = (__bf16)u[0]; r[1] = (__bf16)u[1]; r[2] = (__bf16)u[2]; r[3] = (__bf16)u[3];
  r[4] = (__bf16)v[0]; r[5] = (__bf16)v[1]; r[6] = (__bf16)v[2]; r[7] = (__bf16)v[3];
  return r;
}
// 16B device-coherent h load: two relaxed agent-scope u64 atomics.
__device__ __forceinline__ bf16x8 ld_h16(const ushort_t* p) {
  union { u64 q[2]; bf16x8 v; } x;
  x.q[0] = __hip_atomic_load((const u64*)p,     __ATOMIC_RELAXED, __HIP_MEMORY_SCOPE_AGENT);
  x.q[1] = __hip_atomic_load((const u64*)p + 1, __ATOMIC_RELAXED, __HIP_MEMORY_SCOPE_AGENT);
  return x.v;
}

// ---------------------------------------------------------------------------
// Dtype probe (fp32 vs bf16 inputs) -> flag in d_ws.
// ---------------------------------------------------------------------------
__global__ void detect(const ushort_t* w, unsigned* flag) {
  if (threadIdx.x == 0) {
    unsigned f = 0;
    for (int i = 0; i < 128; ++i) {
      float v = b2f(w[i]);
      if (!(v * v < 1.f)) f = 1;    // catches NaN too
    }
    *flag = f;
  }
}

// ---------------------------------------------------------------------------
// Recurrent kernel. 2-D decomposition: bg = wg & 7 owns batch rows
// [bg*32, bg*32+32); ug = wg >> 3 owns units [ug*32, ug*32+32) (x4 gates).
// h exchange + single-hop all-poll barrier stay WITHIN the 16-WG group.
// h global layout: [ug 16][row 256][unit 32] bf16 (both sides coalesced).
// Weights live in per-wave registers (16 gate-rows x 576 K per wave).
// ---------------------------------------------------------------------------
__global__ __launch_bounds__(NT, 2) void lstm_seq(
    const void* enc_inp, const void* dec_inp,
    const void* eWih, const void* eWhh, const void* ebih, const void* ebhh,
    const void* dWih, const void* dWhh, const void* dbih, const void* dbhh,
    ushort_t* hbuf0, ushort_t* hbuf1,
    unsigned* flags,
    void* dout, const unsigned* mode)
{
  __shared__ __align__(16) char Hs[32768];      // staged h: [ks 16][row 32][col 32] bf16, XOR-swizzled
  __shared__ __align__(16) float Zb[B][17];     // per-wave z slabs (wave w -> rows [w*32, w*32+32))
  __shared__ __align__(16) float Cst[32][33];   // cell state [local row][local unit]
  __shared__ float Bias[128];

  const bool f32m = (*mode != 0);
  char* hid = (char*)dout + (size_t)B * TDEC * OD * (f32m ? 4 : 2);

  const int tid = threadIdx.x;
  const int lane = tid & 63;
  const int w = tid >> 6;          // wave id: owns units [u0w, u0w+4) x 4 gates
  const int wg = blockIdx.x;
  const int bg = wg & 7;           // batch group (round-robin -> same XCD, perf only)
  const int ug = wg >> 3;          // unit group
  const int fm = lane & 15;
  const int q = lane >> 4;
  const int row0 = bg * 32;        // first batch row of this WG
  const int u0w = ug * 32 + w * 4; // first unit of this wave

  for (int i = tid; i < 32 * 33; i += NT) ((float*)Cst)[i] = 0.f;

  bf16x8 bfrag[KI];
  unsigned bstep = 0;

  for (int phase = 0; phase < 2; ++phase) {
    const void* Wih = phase ? dWih : eWih;
    const void* Whh = phase ? dWhh : eWhh;
    const void* bih = phase ? dbih : ebih;
    const void* bhh = phase ? dbhh : ebhh;
    const void* xin = phase ? dec_inp : enc_inp;
    const int T = phase ? TDEC : TENC;
    const int xstr = phase ? (TDEC * DIN) : (TENC * DIN);   // elements

    // per-wave weight fragments straight from global (once per phase):
    // B-fragment row fm <-> gate (fm>>2), unit u0w + (fm&3)
    {
      const int grow = (fm >> 2) * HD + u0w + (fm & 3);
      for (int i = 0; i < KI; ++i) {
        union { ushort_t s[8]; bf16x8 v; } uf;
        const int k0 = i * 32 + q * 8;
#pragma unroll
        for (int e = 0; e < 8; ++e) {
          const int k = k0 + e;
          float wv = (k < HD) ? ld_elem(Whh, (size_t)grow * HD + k, f32m)
                              : ld_elem(Wih, (size_t)grow * DIN + (k - HD), f32m);
          uf.s[e] = f2b(wv);
        }
        bfrag[i] = uf.v;
      }
    }
    if (tid < 128) {
      const int w_ = tid >> 4, n = tid & 15;
      const int grow = (n >> 2) * HD + ug * 32 + w_ * 4 + (n & 3);
      Bias[tid] = ld_elem(bih, grow, f32m) + ld_elem(bhh, grow, f32m);
    }
    __syncthreads();   // Bias (and first-phase Cst) ready

    for (int t = 0; t < T; ++t) {
      const ushort_t* hcur = (bstep & 1) ? hbuf1 : hbuf0;
      ushort_t* hnxt = (bstep & 1) ? hbuf0 : hbuf1;

      // ---- stage h[row0..row0+32)[0..512) into LDS (32 KB, coalesced) ----
#pragma unroll
      for (int j = 0; j < 4; ++j) {
        const int o = (j * NT + tid) * 16;      // linear byte offset in region
        const int ks = o >> 11;                 // source unit-group block
        const int rem = o & 2047;               // row*64 + col*2
        const int r = rem >> 6;
        const int od = o ^ ((r & 7) << 4);      // bank-conflict swizzle
        *(bf16x8*)(Hs + od) =
            ld_h16(hcur + (size_t)ks * (B * 32) + (size_t)row0 * 32 + (rem >> 1));
      }
      __syncthreads();

      f32x4 acc0 = {0.f, 0.f, 0.f, 0.f}, acc1 = {0.f, 0.f, 0.f, 0.f};
      const int sw = (fm & 7) << 4;
#pragma unroll
      for (int i = 0; i < 16; ++i) {
        bf16x8 a0 = *(const bf16x8*)(Hs + ((i * 2048 + fm * 64 + q * 16) ^ sw));
        bf16x8 a1 = *(const bf16x8*)(Hs + ((i * 2048 + (16 + fm) * 64 + q * 16) ^ sw));
        acc0 = __builtin_amdgcn_mfma_f32_16x16x32_bf16(a0, bfrag[i], acc0, 0, 0, 0);
        acc1 = __builtin_amdgcn_mfma_f32_16x16x32_bf16(a1, bfrag[i], acc1, 0, 0, 0);
      }
      // x part (k = 512..575): read-only input, normal cached loads (L1-shared)
      if (!f32m) {
        const ushort_t* x0 = (const ushort_t*)xin + (size_t)(row0 + fm) * xstr + t * DIN;
        const ushort_t* x1 = (const ushort_t*)xin + (size_t)(row0 + 16 + fm) * xstr + t * DIN;
#pragma unroll
        for (int i = 16; i < KI; ++i) {
          const int xo = (i - 16) * 32 + q * 8;
          bf16x8 a0 = *(const bf16x8*)(x0 + xo);
          bf16x8 a1 = *(const bf16x8*)(x1 + xo);
          acc0 = __builtin_amdgcn_mfma_f32_16x16x32_bf16(a0, bfrag[i], acc0, 0, 0, 0);
          acc1 = __builtin_amdgcn_mfma_f32_16x16x32_bf16(a1, bfrag[i], acc1, 0, 0, 0);
        }
      } else {
        const float* x0 = (const float*)xin + (size_t)(row0 + fm) * xstr + t * DIN;
        const float* x1 = (const float*)xin + (size_t)(row0 + 16 + fm) * xstr + t * DIN;
#pragma unroll
        for (int i = 16; i < KI; ++i) {
          const int xo = (i - 16) * 32 + q * 8;
          bf16x8 a0 = cvt8(x0 + xo);
          bf16x8 a1 = cvt8(x1 + xo);
          acc0 = __builtin_amdgcn_mfma_f32_16x16x32_bf16(a0, bfrag[i], acc0, 0, 0, 0);
          acc1 = __builtin_amdgcn_mfma_f32_16x16x32_bf16(a1, bfrag[i], acc1, 0, 0, 0);
        }
      }

      // z -> LDS (wave-local slab); C/D layout: col=lane&15, row=q*4+r
#pragma unroll
      for (int r = 0; r < 4; ++r) {
        Zb[w * 32 + q * 4 + r][fm] = acc0[r];
        Zb[w * 32 + 16 + q * 4 + r][fm] = acc1[r];
      }
      // cell update: each lane handles 2 consecutive (row, unit) pairs = 1 uint
      {
        const int idx0 = lane * 2;
        const int bl = idx0 >> 2, ub = idx0 & 3;   // ub in {0, 2}
        const int zr = w * 32 + bl;
        float h2v[2];
#pragma unroll
        for (int p = 0; p < 2; ++p) {
          const int u = ub + p;
          float zi = Zb[zr][u]      + Bias[w * 16 + u];
          float zf = Zb[zr][4 + u]  + Bias[w * 16 + 4 + u];
          float zg = Zb[zr][8 + u]  + Bias[w * 16 + 8 + u];
          float zo = Zb[zr][12 + u] + Bias[w * 16 + 12 + u];
          float c = Cst[bl][w * 4 + u];
          float c2 = sigmf(zf) * c + sigmf(zi) * tanhf_fast(zg);
          h2v[p] = sigmf(zo) * tanhf_fast(c2);
          Cst[bl][w * 4 + u] = c2;
        }
        unsigned pk = (unsigned)f2b(h2v[0]) | ((unsigned)f2b(h2v[1]) << 16);
        __hip_atomic_store((unsigned*)(hnxt + (size_t)ug * (B * 32)
                                       + (size_t)(row0 + bl) * 32 + w * 4 + ub),
                           pk, __ATOMIC_RELAXED, __HIP_MEMORY_SCOPE_AGENT);
        if (phase) {
          size_t off = ((size_t)(row0 + bl) * TDEC + t) * HD + ug * 32 + w * 4 + ub;
          if (f32m) {
            float2 f2; f2.x = h2v[0]; f2.y = h2v[1];
            *(float2*)((float*)hid + off) = f2;
          } else {
            *(unsigned*)((ushort_t*)hid + off) = pk;
          }
        }
      }

      // ---- group barrier: single-hop all-poll over the 16 group flags ----
      const unsigned tgt = bstep + 1;
      __syncthreads();                 // drains each wave's stores (vmcnt 0)
      if (tid == 0)
        __hip_atomic_store(&flags[wg * 32], tgt,
                           __ATOMIC_RELAXED, __HIP_MEMORY_SCOPE_AGENT);
      if (tid < NGRP) {
        // group members are wgs {bg + g*8 : g = 0..15}
        while (__hip_atomic_load(&flags[(bg + tid * 8) * 32],
                                 __ATOMIC_RELAXED, __HIP_MEMORY_SCOPE_AGENT) < tgt)
          __builtin_amdgcn_s_sleep(1);
      }
      __syncthreads();
      ++bstep;
    }
  }
}

// ---------------------------------------------------------------------------
// Output projection: Y[16384x512] = Hd[16384x512] @ out_W^T + out_b.
// ---------------------------------------------------------------------------
__global__ __launch_bounds__(NT, 2) void out_proj(
    const void* Wo, const void* bo, void* dout, const unsigned* mode)
{
  __shared__ __align__(16) ushort_t Wc[16][520];
  const bool f32m = (*mode != 0);
  char* Ybase = (char*)dout;
  const char* Hd = Ybase + (size_t)B * TDEC * OD * (f32m ? 4 : 2);

  const int tid = threadIdx.x, lane = tid & 63, w = tid >> 6;
  const int fm = lane & 15, q = lane >> 4;
  const int nb = blockIdx.x & 31, mb = blockIdx.x >> 5;
  const int m0 = mb * 256, n0 = nb * 16;

  for (int idx = tid; idx < 16 * 512; idx += NT) {
    int n = idx >> 9, k = idx & 511;
    Wc[n][k] = f2b(ld_elem(Wo, (size_t)(n0 + n) * 512 + k, f32m));
  }
  __syncthreads();
  bf16x8 bfrag[16];
#pragma unroll
  for (int i = 0; i < 16; ++i) bfrag[i] = *(const bf16x8*)&Wc[fm][i * 32 + q * 8];

  f32x4 acc0 = {0.f, 0.f, 0.f, 0.f}, acc1 = {0.f, 0.f, 0.f, 0.f};
  if (!f32m) {
    const ushort_t* a0p = (const ushort_t*)Hd + (size_t)(m0 + w * 32 + fm) * 512;
    const ushort_t* a1p = (const ushort_t*)Hd + (size_t)(m0 + w * 32 + 16 + fm) * 512;
#pragma unroll
    for (int i = 0; i < 16; ++i) {
      int ko = i * 32 + q * 8;
      bf16x8 a0 = *(const bf16x8*)(a0p + ko);
      bf16x8 a1 = *(const bf16x8*)(a1p + ko);
      acc0 = __builtin_amdgcn_mfma_f32_16x16x32_bf16(a0, bfrag[i], acc0, 0, 0, 0);
      acc1 = __builtin_amdgcn_mfma_f32_16x16x32_bf16(a1, bfrag[i], acc1, 0, 0, 0);
    }
  } else {
    const float* a0p = (const float*)Hd + (size_t)(m0 + w * 32 + fm) * 512;
    const float* a1p = (const float*)Hd + (size_t)(m0 + w * 32 + 16 + fm) * 512;
#pragma unroll
    for (int i = 0; i < 16; ++i) {
      int ko = i * 32 + q * 8;
      bf16x8 a0 = cvt8(a0p + ko);
      bf16x8 a1 = cvt8(a1p + ko);
      acc0 = __builtin_amdgcn_mfma_f32_16x16x32_bf16(a0, bfrag[i], acc0, 0, 0, 0);
      acc1 = __builtin_amdgcn_mfma_f32_16x16x32_bf16(a1, bfrag[i], acc1, 0, 0, 0);
    }
  }
  float bias = ld_elem(bo, n0 + fm, f32m);
#pragma unroll
  for (int r = 0; r < 4; ++r) {
    size_t off0 = (size_t)(m0 + w * 32 + q * 4 + r) * 512 + n0 + fm;
    size_t off1 = off0 + (size_t)16 * 512;
    float v0 = acc0[r] + bias, v1 = acc1[r] + bias;
    if (f32m) { ((float*)Ybase)[off0] = v0; ((float*)Ybase)[off1] = v1; }
    else      { ((ushort_t*)Ybase)[off0] = f2b(v0); ((ushort_t*)Ybase)[off1] = f2b(v1); }
  }
}

extern "C" void kernel_launch(void* const* d_in, const int* in_sizes, int n_in,
                              void* d_out, int out_size, void* d_ws, size_t ws_size,
                              hipStream_t stream) {
  (void)in_sizes; (void)n_in; (void)out_size; (void)ws_size;
  const void* enc_inp = d_in[0];
  const void* dec_inp = d_in[1];
  const void* eWih = d_in[2];
  const void* eWhh = d_in[3];
  const void* ebih = d_in[4];
  const void* ebhh = d_in[5];
  const void* dWih = d_in[6];
  const void* dWhh = d_in[7];
  const void* dbih = d_in[8];
  const void* dbhh = d_in[9];
  const void* outW = d_in[10];
  const void* outb = d_in[11];

  unsigned* flag = (unsigned*)d_ws;

  // scratch inside the dec_outputs region of d_out (overwritten by out_proj):
  //   [0,128)        : unused
  //   [128, 128+16K) : 128 flag lines (128 B apart)
  //   [32K, 32K+256K): hbuf0 (bf16)   [+256K..]: hbuf1
  char* ob = (char*)d_out;
  unsigned* flags = (unsigned*)(ob + 128);
  ushort_t* hbuf0 = (ushort_t*)(ob + 32768);
  ushort_t* hbuf1 = (ushort_t*)(ob + 32768 + (size_t)B * HD * 2);

  // zero flags/hbuf0 (initial h = 0); hbuf1 fully written at step 0
  hipMemsetAsync(d_out, 0, 32768 + (size_t)B * HD * 2, stream);

  detect<<<1, 64, 0, stream>>>((const ushort_t*)eWhh, flag);
  lstm_seq<<<GG, NT, 0, stream>>>(enc_inp, dec_inp, eWih, eWhh, ebih, ebhh,
                                  dWih, dWhh, dbih, dbhh,
                                  hbuf0, hbuf1, flags, d_out, flag);
  out_proj<<<dim3(64 * 32), NT, 0, stream>>>(outW, outb, d_out, flag);
}

// Round 2
// 2345.415 us; speedup vs baseline: 4.4735x; 1.5573x over previous
//
#include <hip/hip_runtime.h>

typedef unsigned short ushort_t;
typedef unsigned long long u64;
typedef __attribute__((ext_vector_type(8))) __bf16 bf16x8;
typedef __attribute__((ext_vector_type(4))) float f32x4;

#define B 256
#define TENC 512
#define TDEC 64
#define DIN 64
#define HD 512
#define OD 512
#define GG 256          // 16 batch-groups x 16 unit-groups
#define NGRP 16         // WGs per batch-group (unit-groups)
#define NBG 16          // batch groups
#define KTOT 576        // 512 (h) + 64 (x)
#define KI 18           // K iters of 32
#define NT 512          // threads per block
#define ZPITCH 132      // Zb row pitch in floats (bank-friendly)

__device__ __forceinline__ float b2f(ushort_t v) {
  union { unsigned u; float f; } x; x.u = ((unsigned)v) << 16; return x.f;
}
__device__ __forceinline__ ushort_t f2b(float f) {
  union { float f; unsigned u; } x; x.f = f;
  unsigned r = x.u + 0x7fffu + ((x.u >> 16) & 1u);   // RNE
  return (ushort_t)(r >> 16);
}
__device__ __forceinline__ float sigmf(float x) { return 1.f / (1.f + __expf(-x)); }
__device__ __forceinline__ float tanhf_fast(float x) {
  float e = __expf(2.f * x);
  return 1.f - 2.f / (e + 1.f);
}
__device__ __forceinline__ float ld_elem(const void* p, size_t i, bool f32) {
  return f32 ? ((const float*)p)[i] : b2f(((const ushort_t*)p)[i]);
}
__device__ __forceinline__ bf16x8 cvt8(const float* f) {
  f32x4 u = *(const f32x4*)f, v = *(const f32x4*)(f + 4);
  bf16x8 r;
  r[0] = (__bf16)u[0]; r[1] = (__bf16)u[1]; r[2] = (__bf16)u[2]; r[3] = (__bf16)u[3];
  r[4] = (__bf16)v[0]; r[5] = (__bf16)v[1]; r[6] = (__bf16)v[2]; r[7] = (__bf16)v[3];
  return r;
}
// 16B device-coherent h load: two relaxed agent-scope u64 atomics.
__device__ __forceinline__ bf16x8 ld_h16(const ushort_t* p) {
  union { u64 q[2]; bf16x8 v; } x;
  x.q[0] = __hip_atomic_load((const u64*)p,     __ATOMIC_RELAXED, __HIP_MEMORY_SCOPE_AGENT);
  x.q[1] = __hip_atomic_load((const u64*)p + 1, __ATOMIC_RELAXED, __HIP_MEMORY_SCOPE_AGENT);
  return x.v;
}

// ---------------------------------------------------------------------------
// Dtype probe (fp32 vs bf16 inputs) -> flag in d_ws.
// ---------------------------------------------------------------------------
__global__ void detect(const ushort_t* w, unsigned* flag) {
  if (threadIdx.x == 0) {
    unsigned f = 0;
    for (int i = 0; i < 128; ++i) {
      float v = b2f(w[i]);
      if (!(v * v < 1.f)) f = 1;    // catches NaN too
    }
    *flag = f;
  }
}

// ---------------------------------------------------------------------------
// Recurrent kernel. 2-D decomposition: bg = wg & 15 owns batch rows
// [bg*16, bg*16+16); ug = wg >> 4 owns units [ug*32, ug*32+32) (x4 gates).
// h exchange + single-hop all-poll barrier stay WITHIN the 16-WG group
// (same bg, all ug -> same XCD under round-robin placement, perf only).
// h global layout: [ug 16][row 256][unit 32] bf16 (both sides coalesced).
// Weights in per-wave registers (16 gate-cols x 576 K per wave).
// Wave w: output tile = 16 rows x 16 gate-cols (units w*4..w*4+4, 4 gates).
// Cell state: one (row, unit) pair per lane, held in a REGISTER.
// ---------------------------------------------------------------------------
__global__ __launch_bounds__(NT, 2) void lstm_seq(
    const void* enc_inp, const void* dec_inp,
    const void* eWih, const void* eWhh, const void* ebih, const void* ebhh,
    const void* dWih, const void* dWhh, const void* dbih, const void* dbhh,
    ushort_t* hbuf0, ushort_t* hbuf1,
    unsigned* flags,
    void* dout, const unsigned* mode)
{
  __shared__ __align__(16) char Hs[16384];       // staged h: [ks 16][row 16][col 32] bf16, XOR-swizzled
  __shared__ __align__(16) float Zb[16 * ZPITCH]; // z slab: [row 16][gatecol 128] pitch 132
  __shared__ float Bias[128];

  const bool f32m = (*mode != 0);
  char* hid = (char*)dout + (size_t)B * TDEC * OD * (f32m ? 4 : 2);

  const int tid = threadIdx.x;
  const int lane = tid & 63;
  const int w = tid >> 6;          // wave id: owns units [u0w, u0w+4) x 4 gates
  const int wg = blockIdx.x;
  const int bg = wg & 15;          // batch group (group members share XCD, perf only)
  const int ug = wg >> 4;          // unit group
  const int fm = lane & 15;
  const int q = lane >> 4;
  const int row0 = bg * 16;        // first batch row of this WG
  const int u0w = ug * 32 + w * 4; // first unit of this wave

  // cell-update lane mapping: one (row, unit) pair per lane
  const int crow = lane >> 2;      // 0..15
  const int cdu = lane & 3;        // unit offset within wave's 4 units
  float creg = 0.f;                // cell state c(row0+crow, u0w+cdu)

  bf16x8 bfrag[KI];
  unsigned bstep = 0;

  for (int phase = 0; phase < 2; ++phase) {
    const void* Wih = phase ? dWih : eWih;
    const void* Whh = phase ? dWhh : eWhh;
    const void* bih = phase ? dbih : ebih;
    const void* bhh = phase ? dbhh : ebhh;
    const void* xin = phase ? dec_inp : enc_inp;
    const int T = phase ? TDEC : TENC;
    const int xstr = phase ? (TDEC * DIN) : (TENC * DIN);   // elements

    // per-wave weight fragments straight from global (once per phase):
    // B-fragment row fm <-> gate (fm>>2), unit u0w + (fm&3)
    {
      const int grow = (fm >> 2) * HD + u0w + (fm & 3);
      for (int i = 0; i < KI; ++i) {
        union { ushort_t s[8]; bf16x8 v; } uf;
        const int k0 = i * 32 + q * 8;
#pragma unroll
        for (int e = 0; e < 8; ++e) {
          const int k = k0 + e;
          float wv = (k < HD) ? ld_elem(Whh, (size_t)grow * HD + k, f32m)
                              : ld_elem(Wih, (size_t)grow * DIN + (k - HD), f32m);
          uf.s[e] = f2b(wv);
        }
        bfrag[i] = uf.v;
      }
    }
    if (tid < 128) {
      const int w_ = tid >> 4, n = tid & 15;
      const int grow = (n >> 2) * HD + ug * 32 + w_ * 4 + (n & 3);
      Bias[tid] = ld_elem(bih, grow, f32m) + ld_elem(bhh, grow, f32m);
    }
    __syncthreads();   // Bias ready

    for (int t = 0; t < T; ++t) {
      const ushort_t* hcur = (bstep & 1) ? hbuf1 : hbuf0;
      ushort_t* hnxt = (bstep & 1) ? hbuf0 : hbuf1;

      // ---- stage h[row0..row0+16)[0..512) into LDS (16 KB, coalesced) ----
#pragma unroll
      for (int j = 0; j < 2; ++j) {
        const int o = (j * NT + tid) * 16;      // linear byte offset in region
        const int ks = o >> 10;                 // source unit-group block
        const int rem = o & 1023;               // row*64 + col*2
        const int r = rem >> 6;
        const int od = o ^ ((r & 7) << 4);      // bank-conflict swizzle
        *(bf16x8*)(Hs + od) =
            ld_h16(hcur + (size_t)ks * (B * 32) + (size_t)row0 * 32 + (rem >> 1));
      }
      __syncthreads();

      f32x4 acc = {0.f, 0.f, 0.f, 0.f};
      const int sw = (fm & 7) << 4;
#pragma unroll
      for (int i = 0; i < 16; ++i) {
        bf16x8 a = *(const bf16x8*)(Hs + ((i * 1024 + fm * 64 + q * 16) ^ sw));
        acc = __builtin_amdgcn_mfma_f32_16x16x32_bf16(a, bfrag[i], acc, 0, 0, 0);
      }
      // x part (k = 512..575): read-only input, normal cached loads
      if (!f32m) {
        const ushort_t* x0 = (const ushort_t*)xin + (size_t)(row0 + fm) * xstr + t * DIN;
#pragma unroll
        for (int i = 16; i < KI; ++i) {
          bf16x8 a = *(const bf16x8*)(x0 + (i - 16) * 32 + q * 8);
          acc = __builtin_amdgcn_mfma_f32_16x16x32_bf16(a, bfrag[i], acc, 0, 0, 0);
        }
      } else {
        const float* x0 = (const float*)xin + (size_t)(row0 + fm) * xstr + t * DIN;
#pragma unroll
        for (int i = 16; i < KI; ++i) {
          bf16x8 a = cvt8(x0 + (i - 16) * 32 + q * 8);
          acc = __builtin_amdgcn_mfma_f32_16x16x32_bf16(a, bfrag[i], acc, 0, 0, 0);
        }
      }

      // z -> LDS; C/D layout: col=lane&15 (gate-col fm), row=q*4+r (batch row)
#pragma unroll
      for (int r = 0; r < 4; ++r)
        Zb[(q * 4 + r) * ZPITCH + w * 16 + fm] = acc[r];

      // cell update: lane -> (row = crow, unit = u0w + cdu); c in register
      float h2;
      {
        const float* zr = &Zb[crow * ZPITCH + w * 16];
        float zi = zr[cdu]      + Bias[w * 16 + cdu];
        float zf = zr[4 + cdu]  + Bias[w * 16 + 4 + cdu];
        float zg = zr[8 + cdu]  + Bias[w * 16 + 8 + cdu];
        float zo = zr[12 + cdu] + Bias[w * 16 + 12 + cdu];
        float c2 = sigmf(zf) * creg + sigmf(zi) * tanhf_fast(zg);
        h2 = sigmf(zo) * tanhf_fast(c2);
        creg = c2;
      }
      // pack pairs (cdu, cdu^1) and publish from even-cdu lanes
      {
        float hn = __shfl_xor(h2, 1);
        if ((cdu & 1) == 0) {
          unsigned pk = (unsigned)f2b(h2) | ((unsigned)f2b(hn) << 16);
          __hip_atomic_store((unsigned*)(hnxt + (size_t)ug * (B * 32)
                                         + (size_t)(row0 + crow) * 32 + w * 4 + cdu),
                             pk, __ATOMIC_RELAXED, __HIP_MEMORY_SCOPE_AGENT);
          if (phase) {
            size_t off = ((size_t)(row0 + crow) * TDEC + t) * HD + u0w + cdu;
            if (f32m) {
              float2 f2; f2.x = h2; f2.y = hn;
              *(float2*)((float*)hid + off) = f2;
            } else {
              *(unsigned*)((ushort_t*)hid + off) = pk;
            }
          }
        }
      }

      // ---- group barrier: single-hop all-poll over the 16 group flags ----
      const unsigned tgt = bstep + 1;
      __syncthreads();                 // drains each wave's stores (vmcnt 0)
      if (tid == 0)
        __hip_atomic_store(&flags[wg * 32], tgt,
                           __ATOMIC_RELAXED, __HIP_MEMORY_SCOPE_AGENT);
      if (tid < NGRP) {
        // group members are wgs {bg + g*16 : g = 0..15}
        while (__hip_atomic_load(&flags[(bg + tid * 16) * 32],
                                 __ATOMIC_RELAXED, __HIP_MEMORY_SCOPE_AGENT) < tgt)
          __builtin_amdgcn_s_sleep(1);
      }
      __syncthreads();
      ++bstep;
    }
  }
}

// ---------------------------------------------------------------------------
// Output projection: Y[16384x512] = Hd[16384x512] @ out_W^T + out_b.
// ---------------------------------------------------------------------------
__global__ __launch_bounds__(NT, 2) void out_proj(
    const void* Wo, const void* bo, void* dout, const unsigned* mode)
{
  __shared__ __align__(16) ushort_t Wc[16][520];
  const bool f32m = (*mode != 0);
  char* Ybase = (char*)dout;
  const char* Hd = Ybase + (size_t)B * TDEC * OD * (f32m ? 4 : 2);

  const int tid = threadIdx.x, lane = tid & 63, w = tid >> 6;
  const int fm = lane & 15, q = lane >> 4;
  const int nb = blockIdx.x & 31, mb = blockIdx.x >> 5;
  const int m0 = mb * 256, n0 = nb * 16;

  for (int idx = tid; idx < 16 * 512; idx += NT) {
    int n = idx >> 9, k = idx & 511;
    Wc[n][k] = f2b(ld_elem(Wo, (size_t)(n0 + n) * 512 + k, f32m));
  }
  __syncthreads();
  bf16x8 bfrag[16];
#pragma unroll
  for (int i = 0; i < 16; ++i) bfrag[i] = *(const bf16x8*)&Wc[fm][i * 32 + q * 8];

  f32x4 acc0 = {0.f, 0.f, 0.f, 0.f}, acc1 = {0.f, 0.f, 0.f, 0.f};
  if (!f32m) {
    const ushort_t* a0p = (const ushort_t*)Hd + (size_t)(m0 + w * 32 + fm) * 512;
    const ushort_t* a1p = (const ushort_t*)Hd + (size_t)(m0 + w * 32 + 16 + fm) * 512;
#pragma unroll
    for (int i = 0; i < 16; ++i) {
      int ko = i * 32 + q * 8;
      bf16x8 a0 = *(const bf16x8*)(a0p + ko);
      bf16x8 a1 = *(const bf16x8*)(a1p + ko);
      acc0 = __builtin_amdgcn_mfma_f32_16x16x32_bf16(a0, bfrag[i], acc0, 0, 0, 0);
      acc1 = __builtin_amdgcn_mfma_f32_16x16x32_bf16(a1, bfrag[i], acc1, 0, 0, 0);
    }
  } else {
    const float* a0p = (const float*)Hd + (size_t)(m0 + w * 32 + fm) * 512;
    const float* a1p = (const float*)Hd + (size_t)(m0 + w * 32 + 16 + fm) * 512;
#pragma unroll
    for (int i = 0; i < 16; ++i) {
      int ko = i * 32 + q * 8;
      bf16x8 a0 = cvt8(a0p + ko);
      bf16x8 a1 = cvt8(a1p + ko);
      acc0 = __builtin_amdgcn_mfma_f32_16x16x32_bf16(a0, bfrag[i], acc0, 0, 0, 0);
      acc1 = __builtin_amdgcn_mfma_f32_16x16x32_bf16(a1, bfrag[i], acc1, 0, 0, 0);
    }
  }
  float bias = ld_elem(bo, n0 + fm, f32m);
#pragma unroll
  for (int r = 0; r < 4; ++r) {
    size_t off0 = (size_t)(m0 + w * 32 + q * 4 + r) * 512 + n0 + fm;
    size_t off1 = off0 + (size_t)16 * 512;
    float v0 = acc0[r] + bias, v1 = acc1[r] + bias;
    if (f32m) { ((float*)Ybase)[off0] = v0; ((float*)Ybase)[off1] = v1; }
    else      { ((ushort_t*)Ybase)[off0] = f2b(v0); ((ushort_t*)Ybase)[off1] = f2b(v1); }
  }
}

extern "C" void kernel_launch(void* const* d_in, const int* in_sizes, int n_in,
                              void* d_out, int out_size, void* d_ws, size_t ws_size,
                              hipStream_t stream) {
  (void)in_sizes; (void)n_in; (void)out_size; (void)ws_size;
  const void* enc_inp = d_in[0];
  const void* dec_inp = d_in[1];
  const void* eWih = d_in[2];
  const void* eWhh = d_in[3];
  const void* ebih = d_in[4];
  const void* ebhh = d_in[5];
  const void* dWih = d_in[6];
  const void* dWhh = d_in[7];
  const void* dbih = d_in[8];
  const void* dbhh = d_in[9];
  const void* outW = d_in[10];
  const void* outb = d_in[11];

  unsigned* flag = (unsigned*)d_ws;

  // scratch inside the dec_outputs region of d_out (overwritten by out_proj):
  //   [128, 128+32K) : 256 flag lines (128 B apart)
  //   [64K, 64K+256K): hbuf0 (bf16)   [+256K..]: hbuf1
  char* ob = (char*)d_out;
  unsigned* flags = (unsigned*)(ob + 128);
  ushort_t* hbuf0 = (ushort_t*)(ob + 65536);
  ushort_t* hbuf1 = (ushort_t*)(ob + 65536 + (size_t)B * HD * 2);

  // zero flags/hbuf0 (initial h = 0); hbuf1 fully written at step 0
  hipMemsetAsync(d_out, 0, 65536 + (size_t)B * HD * 2, stream);

  detect<<<1, 64, 0, stream>>>((const ushort_t*)eWhh, flag);
  lstm_seq<<<GG, NT, 0, stream>>>(enc_inp, dec_inp, eWih, eWhh, ebih, ebhh,
                                  dWih, dWhh, dbih, dbhh,
                                  hbuf0, hbuf1, flags, d_out, flag);
  out_proj<<<dim3(64 * 32), NT, 0, stream>>>(outW, outb, d_out, flag);
}